// Round 6
// baseline (175.483 us; speedup 1.0000x reference)
//
#include <hip/hip_runtime.h>
#include <math.h>

#define B_ 2
#define S_ 2048
#define DIM_ 512
#define H_ 8
#define DH_ 64
#define QBLK 16
#define KTILE 32
#define PSTRIDE 2056   // bf16 row stride; 16B-aligned rows

typedef __bf16 bf16x8 __attribute__((ext_vector_type(8)));
typedef float f32x4 __attribute__((ext_vector_type(4)));
typedef float vf4 __attribute__((ext_vector_type(4)));
typedef unsigned short ushort_t;
typedef ushort_t ushort8 __attribute__((ext_vector_type(8)));

__device__ __forceinline__ ushort_t f2bf(float f) {
    union { float f; unsigned u; } v; v.f = f;
    unsigned u = v.u;
    return (ushort_t)((u + 0x7FFFu + ((u >> 16) & 1u)) >> 16);
}
__device__ __forceinline__ float bf2f(ushort_t u) {
    union { unsigned u; float f; } v; v.u = ((unsigned)u) << 16;
    return v.f;
}
__device__ __forceinline__ bf16x8 cvt8(float4 x, float4 y) {
    bf16x8 r;
    r[0] = (__bf16)x.x; r[1] = (__bf16)x.y; r[2] = (__bf16)x.z; r[3] = (__bf16)x.w;
    r[4] = (__bf16)y.x; r[5] = (__bf16)y.y; r[6] = (__bf16)y.z; r[7] = (__bf16)y.w;
    return r;
}

// ---------------------------------------------------------------------------
// Projection via MFMA with fused f32->bf16 convert: C = A @ W^T + b.
// 128 rows x 64 cols per block, 32 rows per wave (B-fragment reuse).
// which 0: queries->Qh, 1: keys->Kh, 2: keys->Vt (transposed)
// ---------------------------------------------------------------------------
__global__ __launch_bounds__(256) void proj_mfma_kernel(
    const float* __restrict__ Qin, const float* __restrict__ Kin,
    const float* __restrict__ Wq, const float* __restrict__ bq,
    const float* __restrict__ Wk, const float* __restrict__ bk,
    const float* __restrict__ Wv, const float* __restrict__ bv,
    ushort_t* __restrict__ Qh, ushort_t* __restrict__ Kh, ushort_t* __restrict__ Vt)
{
    __shared__ float T[128][68];   // transpose staging (which==2 only)

    const int which = blockIdx.z;
    const float* A    = (which == 0) ? Qin : Kin;
    const float* W    = (which == 0) ? Wq : (which == 1 ? Wk : Wv);
    const float* bias = (which == 0) ? bq : (which == 1 ? bk : bv);

    const int r0 = blockIdx.x * 128;
    const int h  = blockIdx.y;
    const int c0 = h * DH_;
    const int tid = threadIdx.x;
    const int w = tid >> 6, l = tid & 63;
    const int lr = l & 15, lg = l >> 4;

    f32x4 acc[2][4] = {};
    const float* arow0 = A + (size_t)(r0 + w * 32 + lr) * DIM_ + lg * 8;
    const float* arow1 = arow0 + (size_t)16 * DIM_;
    const float* wrow0 = W + (size_t)(c0 + lr) * DIM_ + lg * 8;

#pragma unroll 4
    for (int ks = 0; ks < DIM_ / 32; ++ks) {
        bf16x8 a0 = cvt8(*(const float4*)(arow0 + ks * 32), *(const float4*)(arow0 + ks * 32 + 4));
        bf16x8 a1 = cvt8(*(const float4*)(arow1 + ks * 32), *(const float4*)(arow1 + ks * 32 + 4));
#pragma unroll
        for (int ct = 0; ct < 4; ++ct) {
            const float* wp = wrow0 + (size_t)ct * 16 * DIM_ + ks * 32;
            bf16x8 bfr = cvt8(*(const float4*)(wp), *(const float4*)(wp + 4));
            acc[0][ct] = __builtin_amdgcn_mfma_f32_16x16x32_bf16(a0, bfr, acc[0][ct], 0, 0, 0);
            acc[1][ct] = __builtin_amdgcn_mfma_f32_16x16x32_bf16(a1, bfr, acc[1][ct], 0, 0, 0);
        }
    }

    const int bb = r0 >> 11;
    const int s0 = r0 & (S_ - 1);
    const int n = h * B_ + bb;

    if (which < 2) {
        ushort_t* OUT = (which == 0) ? Qh : Kh;
#pragma unroll
        for (int rg = 0; rg < 2; ++rg) {
#pragma unroll
            for (int ct = 0; ct < 4; ++ct) {
                int d = ct * 16 + lr;
                float bi = bias[c0 + d];
#pragma unroll
                for (int reg = 0; reg < 4; ++reg) {
                    int s = s0 + w * 32 + rg * 16 + lg * 4 + reg;
                    OUT[((size_t)n * S_ + s) * DH_ + d] = f2bf(acc[rg][ct][reg] + bi);
                }
            }
        }
    } else {
#pragma unroll
        for (int rg = 0; rg < 2; ++rg) {
#pragma unroll
            for (int ct = 0; ct < 4; ++ct) {
                int d = ct * 16 + lr;
                float bi = bias[c0 + d];
#pragma unroll
                for (int reg = 0; reg < 4; ++reg)
                    T[w * 32 + rg * 16 + lg * 4 + reg][d] = acc[rg][ct][reg] + bi;
            }
        }
        __syncthreads();
        int d = tid & 63, sc = tid >> 6;
        ushort8 o[4];
#pragma unroll
        for (int i = 0; i < 32; ++i)
            ((ushort_t*)o)[i] = f2bf(T[sc * 32 + i][d]);
        ushort8* dst = (ushort8*)(Vt + ((size_t)n * DH_ + d) * S_ + s0 + sc * 32);
        dst[0] = o[0]; dst[1] = o[1]; dst[2] = o[2]; dst[3] = o[3];
    }
}

// ---------------------------------------------------------------------------
// Fused attention, single pass, 8 waves (512 thr). Block = 16 q-rows x one n.
// Score sweep split 8 ways; one barrier; then waves 0-3 do PV while waves
// 4-7 stream the normalized attnw rows (phase overlap).
// ---------------------------------------------------------------------------
__global__ __launch_bounds__(512, 4) void attn_mfma_kernel(
    const ushort_t* __restrict__ Qh, const ushort_t* __restrict__ Kh,
    const ushort_t* __restrict__ Vt, const int* __restrict__ causp,
    float* __restrict__ outp, float* __restrict__ attnw)
{
    __shared__ ushort_t Pl[QBLK][PSTRIDE];   // 65,792 B
    __shared__ float sums[8][QBLK];

    const int bid = blockIdx.x;
    const int swz = (bid & 7) * 256 + (bid >> 3);   // XCD-bijective (2048 = 8*256)
    const int n = swz >> 7;
    const int qt = 127 - (swz & 127);        // LPT: heaviest first
    const int h = n / B_, b = n % B_;
    const int q0 = qt * QBLK;
    const int causal = causp[0];
    const int tid = threadIdx.x;
    const int w = tid >> 6, l = tid & 63;
    const int lr = l & 15, lg = l >> 4;

    const int kmax = causal ? (q0 + QBLK) : S_;
    const int kend = ((kmax + KTILE - 1) / KTILE) * KTILE;

    float* attrow = attnw + ((size_t)((b * H_ + h) * S_ + q0)) * S_;

    // ---- early zero-fill of attnw cols [kend, S): drains under compute
    if (kend < S_) {
        int zc = (S_ - kend) >> 2;
        vf4 z = {0.f, 0.f, 0.f, 0.f};
        for (int idx = tid; idx < QBLK * zc; idx += 512) {
            int r = idx / zc, c4 = (idx % zc) << 2;
            __builtin_nontemporal_store(z, (vf4*)&attrow[(size_t)r * S_ + kend + c4]);
        }
    }

    // ---- Q fragments (rows q0+lr, dh = lg*8 + {0,32})
    const ushort_t* qrow = Qh + ((size_t)n * S_ + q0 + lr) * DH_ + lg * 8;
    bf16x8 qa0 = *(const bf16x8*)(qrow);
    bf16x8 qa1 = *(const bf16x8*)(qrow + 32);

    const ushort_t* Kbase = Kh + (size_t)n * S_ * DH_;

    // ---- score sweep: wave w handles 32-col tiles t = w, w+8, ...
    float pl[4] = {0.f, 0.f, 0.f, 0.f};
    for (int kc = w * KTILE; kc < kend; kc += 8 * KTILE) {
        const ushort_t* kra = Kbase + (size_t)(kc + lr) * DH_ + lg * 8;
        const ushort_t* krb = kra + (size_t)16 * DH_;
        f32x4 accA = {}, accB = {};
        accA = __builtin_amdgcn_mfma_f32_16x16x32_bf16(qa0, *(const bf16x8*)(kra),      accA, 0, 0, 0);
        accA = __builtin_amdgcn_mfma_f32_16x16x32_bf16(qa1, *(const bf16x8*)(kra + 32), accA, 0, 0, 0);
        accB = __builtin_amdgcn_mfma_f32_16x16x32_bf16(qa0, *(const bf16x8*)(krb),      accB, 0, 0, 0);
        accB = __builtin_amdgcn_mfma_f32_16x16x32_bf16(qa1, *(const bf16x8*)(krb + 32), accB, 0, 0, 0);
#pragma unroll
        for (int reg = 0; reg < 4; ++reg) {
            int row = lg * 4 + reg;
            int qq = q0 + row;
            int kA = kc + lr, kB = kA + 16;
            float eA = (!causal || kA <= qq) ? __expf(accA[reg] * 0.125f) : 0.f;
            float eB = (!causal || kB <= qq) ? __expf(accB[reg] * 0.125f) : 0.f;
            pl[reg] += eA + eB;
            __bf16 vA = (__bf16)eA, vB = (__bf16)eB;
            Pl[row][kA] = *(ushort_t*)&vA;
            Pl[row][kB] = *(ushort_t*)&vB;
        }
    }

    // per-row partial sums (reduce over the 16 lr-lanes)
#pragma unroll
    for (int reg = 0; reg < 4; ++reg) {
        float v = pl[reg];
        v += __shfl_xor(v, 1); v += __shfl_xor(v, 2);
        v += __shfl_xor(v, 4); v += __shfl_xor(v, 8);
        if (lr == 0) sums[w][lg * 4 + reg] = v;
    }
    __syncthreads();   // the ONLY barrier

    if (w < 4) {
        // ---- PV from LDS bf16 (waves 0-3), d-chunk = w*16
        float inv_r[4];
#pragma unroll
        for (int reg = 0; reg < 4; ++reg) {
            int row = lg * 4 + reg;
            float t = 0.f;
#pragma unroll
            for (int ww = 0; ww < 8; ++ww) t += sums[ww][row];
            inv_r[reg] = 1.f / t;
        }
        f32x4 oacc = {};
        const ushort_t* Vbase = Vt + (size_t)n * DH_ * S_ + (size_t)(w * 16 + lr) * S_;
        for (int kt = 0; kt < kend; kt += KTILE) {
            bf16x8 pa = *(const bf16x8*)&Pl[lr][kt + lg * 8];
            bf16x8 vb = *(const bf16x8*)(Vbase + kt + lg * 8);
            oacc = __builtin_amdgcn_mfma_f32_16x16x32_bf16(pa, vb, oacc, 0, 0, 0);
        }
#pragma unroll
        for (int reg = 0; reg < 4; ++reg) {
            int qq = q0 + lg * 4 + reg;
            __builtin_nontemporal_store(oacc[reg] * inv_r[reg],
                &outp[((size_t)b * S_ + qq) * DIM_ + h * DH_ + w * 16 + lr]);
        }
    } else {
        // ---- normalized attnw write-out (waves 4-7): 4 rows per wave,
        //      64 lanes x ushort8 -> 2 KB contiguous bursts
#pragma unroll
        for (int rr = 0; rr < 4; ++rr) {
            int row = (w - 4) * 4 + rr;
            float t = 0.f;
#pragma unroll
            for (int ww = 0; ww < 8; ++ww) t += sums[ww][row];
            float invw = 1.f / t;
            float* ar = attrow + (size_t)row * S_;
            for (int c = l * 8; c < kend; c += 512) {
                ushort8 pv = *(const ushort8*)&Pl[row][c];
                vf4 o0, o1;
                o0.x = bf2f(pv[0]) * invw; o0.y = bf2f(pv[1]) * invw;
                o0.z = bf2f(pv[2]) * invw; o0.w = bf2f(pv[3]) * invw;
                o1.x = bf2f(pv[4]) * invw; o1.y = bf2f(pv[5]) * invw;
                o1.z = bf2f(pv[6]) * invw; o1.w = bf2f(pv[7]) * invw;
                __builtin_nontemporal_store(o0, (vf4*)&ar[c]);
                __builtin_nontemporal_store(o1, (vf4*)&ar[c + 4]);
            }
        }
    }
}

extern "C" void kernel_launch(void* const* d_in, const int* in_sizes, int n_in,
                              void* d_out, int out_size, void* d_ws, size_t ws_size,
                              hipStream_t stream) {
    const float* queries = (const float*)d_in[0];
    const float* keys    = (const float*)d_in[1];
    const float* Wq = (const float*)d_in[2];
    const float* bq = (const float*)d_in[3];
    const float* Wk = (const float*)d_in[4];
    const float* bk = (const float*)d_in[5];
    const float* Wv = (const float*)d_in[6];
    const float* bv = (const float*)d_in[7];
    const int*   caus = (const int*)d_in[8];

    char* ws = (char*)d_ws;
    ushort_t* Qh = (ushort_t*)ws;      ws += (size_t)H_*B_*S_*DH_*2;   // 4 MB
    ushort_t* Kh = (ushort_t*)ws;      ws += (size_t)H_*B_*S_*DH_*2;   // 4 MB
    ushort_t* Vt = (ushort_t*)ws;      ws += (size_t)H_*B_*DH_*S_*2;   // 4 MB

    float* outp  = (float*)d_out;
    float* attnw = outp + (size_t)B_ * S_ * DIM_;

    proj_mfma_kernel<<<dim3(32, 8, 3), 256, 0, stream>>>(
        queries, keys, Wq, bq, Wk, bk, Wv, bv, Qh, Kh, Vt);

    attn_mfma_kernel<<<2048, 512, 0, stream>>>(Qh, Kh, Vt, caus, outp, attnw);
}